// Round 11
// baseline (124.766 us; speedup 1.0000x reference)
//
#include <hip/hip_runtime.h>

// B=4, CIN=COUT=64, H=W=128, 3x3 deformable conv, fp32 in/out.
// R11: K-split TLP. 1024 blocks (one 8x8 tile each) x 512 threads = 8 waves:
// wave = (pixel-group wq, cin-half). Stage-2 per wave = 9 steps over its 32
// cins (R9's exact loop body — VGPR 64, no spill). Stage-1 computed
// redundantly by both halves (identical values, benign duplicate writes).
// acc halves reduced through LDS red[64][65] which doubles as the epilogue
// transpose buffer. __launch_bounds__(512,8) -> 64 VGPR -> 32 waves/CU
// (8/SIMD, 2x R9's TLP). R10's manual pipeline (spilled, regressed) reverted.

typedef __attribute__((ext_vector_type(8))) short short8x;
typedef __attribute__((ext_vector_type(4))) float float4x;
typedef unsigned short ushort;
typedef unsigned int uint;

__device__ __forceinline__ ushort f2bf(float f) {
    uint b = __float_as_uint(f);
    b += 0x7fffu + ((b >> 16) & 1u);
    return (ushort)(b >> 16);
}
__device__ __forceinline__ float bf2f(ushort u) {
    return __uint_as_float(((uint)u) << 16);
}

// ---------------------------------------------------------------------------
// Prologue: pack weights into MFMA B-fragment order (bf16). (R5 verbatim)
//  Bd [kk(18)][nt(4)][lane(64)][i(8)]: n = nt*16+(lane&15),
//     k = kk*32 + (lane>>4)*8 + i -> k2 = kk>>1, cin = (kk&1)*32+(lane>>4)*8+i
//  Bo [kk(18)][nt(2)][lane][i]: same, n>=18 zero-padded.
// ---------------------------------------------------------------------------
__global__ __launch_bounds__(256) void pack_weights(
    const float* __restrict__ w_def, const float* __restrict__ w_off,
    ushort* __restrict__ Bd, ushort* __restrict__ Bo) {
    int idx = blockIdx.x * 256 + threadIdx.x;
    if (idx < 36864) {
        int i = idx & 7;
        int lane = (idx >> 3) & 63;
        int nt = (idx >> 9) & 3;
        int kk = idx >> 11;
        int n = (nt << 4) + (lane & 15);
        int k2 = kk >> 1;
        int cin = ((kk & 1) << 5) + ((lane >> 4) << 3) + i;
        Bd[idx] = f2bf(w_def[(n * 64 + cin) * 9 + k2]);
    } else if (idx < 36864 + 18432) {
        int d = idx - 36864;
        int i = d & 7;
        int lane = (d >> 3) & 63;
        int nt = (d >> 9) & 1;
        int kk = d >> 10;
        int n = (nt << 4) + (lane & 15);
        int k2 = kk >> 1;
        int cin = ((kk & 1) << 5) + ((lane >> 4) << 3) + i;
        Bo[d] = (n < 18) ? f2bf(w_off[(n * 64 + cin) * 9 + k2]) : (ushort)0;
    }
}

// ---------------------------------------------------------------------------
// Fused kernel. Block = 8x8 pixel tile, 512 threads = 8 waves.
// wq = wv&3 owns pixels 16wq..16wq+15; half = wv>>2 owns cins 32half..+31.
// ---------------------------------------------------------------------------
__global__ __launch_bounds__(512, 8) void dcn_fused(
    const float* __restrict__ x, const ushort* __restrict__ Bd,
    const ushort* __restrict__ Bo, const float* __restrict__ boff,
    const float* __restrict__ bdef, float* __restrict__ out) {

    int tid = threadIdx.x;
    int lane = tid & 63, wv = tid >> 6;
    int wq = wv & 3, half = wv >> 2;
    int blk = blockIdx.x;
    int b = blk >> 8, t = blk & 255;
    int h0 = (t >> 4) << 3, w0 = (t & 15) << 3;

    // Manual shared layout (37008 B): tile 32400 B | offl 4608 B.
    // Epilogue reuses bytes 0..33280 as red[64][65] f32.
    __shared__ __align__(16) char smem[37008];
    ushort* tile = (ushort*)smem;              // [pos(225) stride 72][cin 64]
    float* offl = (float*)(smem + 32400);      // [px 64][ch 18]

    const float* xb = x + ((long)b << 20);

    // ---- stage halo: 450 units = (pos, cin-half), one unit per thread.
    if (tid < 450) {
        int pos = tid >> 1, ch = (tid & 1) << 5;
        int ty = pos / 15, tx = pos - ty * 15;
        int y = h0 - 3 + ty, xx = w0 - 3 + tx;
        bool valid = ((unsigned)y < 128u) & ((unsigned)xx < 128u);
        int yc = min(max(y, 0), 127), xc = min(max(xx, 0), 127);
        const float* gp = xb + ((long)ch << 14) + (yc << 7) + xc;
        uint4* trow = (uint4*)&tile[pos * 72 + ch];
#pragma unroll
        for (int c8 = 0; c8 < 4; ++c8) {
            const float* g8 = gp + (c8 << 17);
            float v[8];
#pragma unroll
            for (int j = 0; j < 8; ++j) v[j] = valid ? g8[j << 14] : 0.f;
            uint4 d;
            d.x = (uint)f2bf(v[0]) | ((uint)f2bf(v[1]) << 16);
            d.y = (uint)f2bf(v[2]) | ((uint)f2bf(v[3]) << 16);
            d.z = (uint)f2bf(v[4]) | ((uint)f2bf(v[5]) << 16);
            d.w = (uint)f2bf(v[6]) | ((uint)f2bf(v[7]) << 16);
            trow[c8] = d;
        }
    }
    __syncthreads();

    int l15 = lane & 15, lq = lane >> 4;
    int p1 = (wq << 4) + l15;          // this lane's A-row pixel
    int plh = p1 >> 3, plw = p1 & 7;

    // ---- stage 1: offset conv via MFMA, full K=576. Both half-groups
    // compute identical results; duplicate offl writes are benign.
    float4x oacc0 = {0.f, 0.f, 0.f, 0.f}, oacc1 = {0.f, 0.f, 0.f, 0.f};
#pragma unroll
    for (int k2 = 0; k2 < 9; ++k2) {
        int kh = k2 / 3, kw = k2 - kh * 3;
        int pos = (plh + 2 + kh) * 15 + (plw + 2 + kw);
        int abase = pos * 72 + (lq << 3);
#pragma unroll
        for (int hf = 0; hf < 2; ++hf) {
            int kk = k2 * 2 + hf;
            short8x a = *(const short8x*)&tile[abase + hf * 32];
            short8x b0 = *(const short8x*)&Bo[(kk * 2 + 0) * 512 + (lane << 3)];
            short8x b1 = *(const short8x*)&Bo[(kk * 2 + 1) * 512 + (lane << 3)];
            oacc0 = __builtin_amdgcn_mfma_f32_16x16x32_bf16(a, b0, oacc0, 0, 0, 0);
            oacc1 = __builtin_amdgcn_mfma_f32_16x16x32_bf16(a, b1, oacc1, 0, 0, 0);
        }
    }
    {   // scatter D (col n = lane&15 [+16], row = lq*4+r) + bias -> offl[px][ch]
        int n0 = l15, n1 = 16 + l15;
        float bo0 = boff[n0];
        float bo1 = (n1 < 18) ? boff[n1] : 0.f;
#pragma unroll
        for (int r = 0; r < 4; ++r) {
            int p = (wq << 4) + (lq << 2) + r;
            offl[p * 18 + n0] = oacc0[r] + bo0;
            if (n1 < 18) offl[p * 18 + n1] = oacc1[r] + bo1;
        }
    }
    __syncthreads();

    // ---- offsets to registers (constant-indexed only) + oob mask
    float2 offr[9];
    uint oobmask = 0;
#pragma unroll
    for (int k2 = 0; k2 < 9; ++k2) {
        offr[k2] = *(const float2*)&offl[p1 * 18 + k2 * 2];
        const int kh = k2 / 3, kw = k2 - kh * 3;
        float sy = (float)(plh + 2 + kh) + offr[k2].x;
        float sx = (float)(plw + 2 + kw) + offr[k2].y;
        int by = (int)floorf(sy), bx = (int)floorf(sx);
        bool oob = ((unsigned)by > 13u) | ((unsigned)bx > 13u);
        oobmask |= oob ? (1u << k2) : 0u;
    }

    // ---- stage 2: 9 steps over this wave's cin-half (R9 loop body)
    float4x acc[4];
#pragma unroll
    for (int nt = 0; nt < 4; ++nt) acc[nt] = (float4x){0.f, 0.f, 0.f, 0.f};

#pragma unroll
    for (int k2 = 0; k2 < 9; ++k2) {
        const int kh = k2 / 3, kw = k2 - kh * 3;
        float sy = (float)(plh + 2 + kh) + offr[k2].x;
        float sx = (float)(plw + 2 + kw) + offr[k2].y;
        float yf = floorf(sy), xf = floorf(sx);
        int by = (int)yf, bx = (int)xf;
        float wy1 = sy - yf, wx1 = sx - xf;
        float wy0 = 1.f - wy1, wx0 = 1.f - wx1;
        float w00 = wy0 * wx0, w01 = wy0 * wx1;
        float w10 = wy1 * wx0, w11 = wy1 * wx1;
        int byc = min(max(by, 0), 13), bxc = min(max(bx, 0), 13);
        int cb = (byc * 15 + bxc) * 72 + (lq << 3) + (half << 5);

        int kk = k2 * 2 + half;
        short8x c00 = *(const short8x*)&tile[cb];
        short8x c01 = *(const short8x*)&tile[cb + 72];
        short8x c10 = *(const short8x*)&tile[cb + 72 * 15];
        short8x c11 = *(const short8x*)&tile[cb + 72 * 16];
        float s[8];
#pragma unroll
        for (int j = 0; j < 8; ++j) {
            s[j] = w00 * bf2f((ushort)c00[j]) + w01 * bf2f((ushort)c01[j])
                 + w10 * bf2f((ushort)c10[j]) + w11 * bf2f((ushort)c11[j]);
        }
        union { short8x v; ushort u[8]; } A;
#pragma unroll
        for (int j = 0; j < 8; ++j) A.u[j] = f2bf(s[j]);
#pragma unroll
        for (int nt = 0; nt < 4; ++nt) {
            short8x bw = *(const short8x*)&Bd[(kk * 4 + nt) * 512 + (lane << 3)];
            acc[nt] = __builtin_amdgcn_mfma_f32_16x16x32_bf16(A.v, bw, acc[nt], 0, 0, 0);
        }
    }

    // ---- cold exactness pass (own half): out-of-tile samples (~8 sigma,
    // never taken on this data). Recomputes from offl (LDS); no dynamic
    // indexing of register arrays (R8 lesson).
    if (__any(oobmask != 0)) {
#pragma unroll 1
        for (int k2 = 0; k2 < 9; ++k2) {
            if (!__any((oobmask >> k2) & 1)) continue;
            bool oob = (oobmask >> k2) & 1;
            const int kh = k2 / 3, kw = k2 - kh * 3;
            float2 od = *(const float2*)&offl[p1 * 18 + k2 * 2];
            float sy = (float)(plh + 2 + kh) + od.x;
            float sx = (float)(plw + 2 + kw) + od.y;
            float yf = floorf(sy), xf = floorf(sx);
            int by = (int)yf, bx = (int)xf;
            float wy1 = sy - yf, wx1 = sx - xf;
            float wy0 = 1.f - wy1, wx0 = 1.f - wx1;
            float w00 = wy0 * wx0, w01 = wy0 * wx1;
            float w10 = wy1 * wx0, w11 = wy1 * wx1;
            int byc = min(max(by, 0), 13), bxc = min(max(bx, 0), 13);
            int cb = (byc * 15 + bxc) * 72 + (lq << 3) + (half << 5);
            int y0g = by + h0 - 3, x0g = bx + w0 - 3;
            int y1g = y0g + 1, x1g = x0g + 1;
            float m00 = ((unsigned)y0g < 128u && (unsigned)x0g < 128u) ? w00 : 0.f;
            float m01 = ((unsigned)y0g < 128u && (unsigned)x1g < 128u) ? w01 : 0.f;
            float m10 = ((unsigned)y1g < 128u && (unsigned)x0g < 128u) ? w10 : 0.f;
            float m11 = ((unsigned)y1g < 128u && (unsigned)x1g < 128u) ? w11 : 0.f;
            int y0c = min(max(y0g, 0), 127), y1c = min(max(y1g, 0), 127);
            int x0c = min(max(x0g, 0), 127), x1c = min(max(x1g, 0), 127);
            int i00 = (y0c << 7) + x0c, i01 = (y0c << 7) + x1c;
            int i10 = (y1c << 7) + x0c, i11 = (y1c << 7) + x1c;
            int kk = k2 * 2 + half;
            int cin0 = (half << 5) + (lq << 3);
            short8x c00 = *(const short8x*)&tile[cb];
            short8x c01 = *(const short8x*)&tile[cb + 72];
            short8x c10 = *(const short8x*)&tile[cb + 72 * 15];
            short8x c11 = *(const short8x*)&tile[cb + 72 * 16];
            float d[8];
#pragma unroll
            for (int j = 0; j < 8; ++j) {
                float sl = w00 * bf2f((ushort)c00[j]) + w01 * bf2f((ushort)c01[j])
                         + w10 * bf2f((ushort)c10[j]) + w11 * bf2f((ushort)c11[j]);
                const float* xp = xb + ((long)(cin0 + j) << 14);
                float sg = m00 * xp[i00] + m01 * xp[i01]
                         + m10 * xp[i10] + m11 * xp[i11];
                d[j] = oob ? (sg - sl) : 0.f;
            }
            union { short8x v; ushort u[8]; } A;
#pragma unroll
            for (int j = 0; j < 8; ++j) A.u[j] = f2bf(d[j]);
#pragma unroll
            for (int nt = 0; nt < 4; ++nt) {
                short8x bw = *(const short8x*)&Bd[(kk * 4 + nt) * 512 + (lane << 3)];
                acc[nt] = __builtin_amdgcn_mfma_f32_16x16x32_bf16(A.v, bw, acc[nt], 0, 0, 0);
            }
        }
    }

    // ---- reduce half pairs through LDS red[64][65] (pad-65: conflict-free;
    // doubles as the transpose layout for the store epilogue)
    __syncthreads();
    float* red = (float*)smem;   // 64*65*4 = 16640 B over tile
    if (half == 1) {
#pragma unroll
        for (int nt = 0; nt < 4; ++nt)
#pragma unroll
            for (int r = 0; r < 4; ++r) {
                int p = (wq << 4) + (lq << 2) + r;
                red[p * 65 + (nt << 4) + l15] = acc[nt][r];
            }
    }
    __syncthreads();
    if (half == 0) {
#pragma unroll
        for (int nt = 0; nt < 4; ++nt)
#pragma unroll
            for (int r = 0; r < 4; ++r) {
                int p = (wq << 4) + (lq << 2) + r;
                red[p * 65 + (nt << 4) + l15] += acc[nt][r];
            }
    }
    __syncthreads();

    // ---- store: 512 threads, thread = (cout n, row q); 2x float4 per thread
    {
        int n = tid >> 3, q = tid & 7;
        float bd = bdef[n];
        float* dst = out + (((long)(b * 64 + n)) << 14) + ((h0 + q) << 7) + w0;
        float v[8];
#pragma unroll
        for (int c = 0; c < 8; ++c) v[c] = red[(q * 8 + c) * 65 + n] + bd;
        float4x s0 = {v[0], v[1], v[2], v[3]};
        float4x s1 = {v[4], v[5], v[6], v[7]};
        *(float4x*)(dst) = s0;
        *(float4x*)(dst + 4) = s1;
    }
}

// ---------------------------------------------------------------------------
extern "C" void kernel_launch(void* const* d_in, const int* in_sizes, int n_in,
                              void* d_out, int out_size, void* d_ws, size_t ws_size,
                              hipStream_t stream) {
    const float* x     = (const float*)d_in[0];  // (4,64,128,128)
    const float* w_off = (const float*)d_in[1];  // (18,64,3,3)
    const float* b_off = (const float*)d_in[2];  // (18,)
    const float* w_def = (const float*)d_in[3];  // (64,64,3,3)
    const float* b_def = (const float*)d_in[4];  // (64,)
    float* out = (float*)d_out;                  // (4,64,128,128)

    ushort* Bd = (ushort*)d_ws;                  // 36864 bf16 = 73728 B
    ushort* Bo = Bd + 36864;                     // 18432 bf16 = 36864 B

    hipLaunchKernelGGL(pack_weights, dim3(216), dim3(256), 0, stream,
                       w_def, w_off, Bd, Bo);
    hipLaunchKernelGGL(dcn_fused, dim3(1024), dim3(512), 0, stream,
                       x, Bd, Bo, b_off, b_def, out);
}

// Round 12
// 110.767 us; speedup vs baseline: 1.1264x; 1.1264x over previous
//
#include <hip/hip_runtime.h>

// B=4, CIN=COUT=64, H=W=128, 3x3 deformable conv, fp32 in/out.
// R12 = R11 with the spill fixed + stage-1 N-split:
//  - __launch_bounds__(512, 4): R11's (512,8) was interpreted as 8 wg/CU ->
//    16 waves/SIMD -> 32-VGPR cap -> spill (WRITE_SIZE 16->41 MB). (512,4)
//    caps at >=64 VGPR; body naturally needs 64; LDS (37.4 KB) caps
//    residency at 4 blocks/CU = 8 waves/SIMD at runtime.
//  - stage-1: wave's cin-half doubles as its n-group: 1 MFMA + 1 B-load per
//    step instead of 2 (removes R11's redundant stage-1).
// Block = 8x8 tile, 512 threads = 8 waves: wave = (px-group wq, cin-half).

typedef __attribute__((ext_vector_type(8))) short short8x;
typedef __attribute__((ext_vector_type(4))) float float4x;
typedef unsigned short ushort;
typedef unsigned int uint;

__device__ __forceinline__ ushort f2bf(float f) {
    uint b = __float_as_uint(f);
    b += 0x7fffu + ((b >> 16) & 1u);
    return (ushort)(b >> 16);
}
__device__ __forceinline__ float bf2f(ushort u) {
    return __uint_as_float(((uint)u) << 16);
}

// ---------------------------------------------------------------------------
// Prologue: pack weights into MFMA B-fragment order (bf16). (R5 verbatim)
//  Bd [kk(18)][nt(4)][lane(64)][i(8)]: n = nt*16+(lane&15),
//     k = kk*32 + (lane>>4)*8 + i -> k2 = kk>>1, cin = (kk&1)*32+(lane>>4)*8+i
//  Bo [kk(18)][nt(2)][lane][i]: same, n>=18 zero-padded.
// ---------------------------------------------------------------------------
__global__ __launch_bounds__(256) void pack_weights(
    const float* __restrict__ w_def, const float* __restrict__ w_off,
    ushort* __restrict__ Bd, ushort* __restrict__ Bo) {
    int idx = blockIdx.x * 256 + threadIdx.x;
    if (idx < 36864) {
        int i = idx & 7;
        int lane = (idx >> 3) & 63;
        int nt = (idx >> 9) & 3;
        int kk = idx >> 11;
        int n = (nt << 4) + (lane & 15);
        int k2 = kk >> 1;
        int cin = ((kk & 1) << 5) + ((lane >> 4) << 3) + i;
        Bd[idx] = f2bf(w_def[(n * 64 + cin) * 9 + k2]);
    } else if (idx < 36864 + 18432) {
        int d = idx - 36864;
        int i = d & 7;
        int lane = (d >> 3) & 63;
        int nt = (d >> 9) & 1;
        int kk = d >> 10;
        int n = (nt << 4) + (lane & 15);
        int k2 = kk >> 1;
        int cin = ((kk & 1) << 5) + ((lane >> 4) << 3) + i;
        Bo[d] = (n < 18) ? f2bf(w_off[(n * 64 + cin) * 9 + k2]) : (ushort)0;
    }
}

// ---------------------------------------------------------------------------
// Fused kernel. Block = 8x8 pixel tile, 512 threads = 8 waves.
// wq = wv&3 owns pixels 16wq..16wq+15; half = wv>>2 owns cins 32half..+31
// (and n-group half in stage 1).
// ---------------------------------------------------------------------------
__global__ __launch_bounds__(512, 4) void dcn_fused(
    const float* __restrict__ x, const ushort* __restrict__ Bd,
    const ushort* __restrict__ Bo, const float* __restrict__ boff,
    const float* __restrict__ bdef, float* __restrict__ out) {

    int tid = threadIdx.x;
    int lane = tid & 63, wv = tid >> 6;
    int wq = wv & 3, half = wv >> 2;
    int blk = blockIdx.x;
    int b = blk >> 8, t = blk & 255;
    int h0 = (t >> 4) << 3, w0 = (t & 15) << 3;

    // Manual shared layout (37008 B): tile 32400 B | offl 4608 B.
    // Epilogue reuses bytes 0..16640 as red[64][65] f32.
    __shared__ __align__(16) char smem[37008];
    ushort* tile = (ushort*)smem;              // [pos(225) stride 72][cin 64]
    float* offl = (float*)(smem + 32400);      // [px 64][ch 18]

    const float* xb = x + ((long)b << 20);

    // ---- stage halo: 450 units = (pos, cin-half), one unit per thread.
    if (tid < 450) {
        int pos = tid >> 1, ch = (tid & 1) << 5;
        int ty = pos / 15, tx = pos - ty * 15;
        int y = h0 - 3 + ty, xx = w0 - 3 + tx;
        bool valid = ((unsigned)y < 128u) & ((unsigned)xx < 128u);
        int yc = min(max(y, 0), 127), xc = min(max(xx, 0), 127);
        const float* gp = xb + ((long)ch << 14) + (yc << 7) + xc;
        uint4* trow = (uint4*)&tile[pos * 72 + ch];
#pragma unroll
        for (int c8 = 0; c8 < 4; ++c8) {
            const float* g8 = gp + (c8 << 17);
            float v[8];
#pragma unroll
            for (int j = 0; j < 8; ++j) v[j] = valid ? g8[j << 14] : 0.f;
            uint4 d;
            d.x = (uint)f2bf(v[0]) | ((uint)f2bf(v[1]) << 16);
            d.y = (uint)f2bf(v[2]) | ((uint)f2bf(v[3]) << 16);
            d.z = (uint)f2bf(v[4]) | ((uint)f2bf(v[5]) << 16);
            d.w = (uint)f2bf(v[6]) | ((uint)f2bf(v[7]) << 16);
            trow[c8] = d;
        }
    }
    __syncthreads();

    int l15 = lane & 15, lq = lane >> 4;
    int p1 = (wq << 4) + l15;          // this lane's A-row pixel
    int plh = p1 >> 3, plw = p1 & 7;

    // ---- stage 1: offset conv via MFMA, N-split: this wave computes only
    // n-group `half` (cols 16*half..16*half+15; half=1 is mostly N-padding).
    // Full K=576: 18 steps x (1 A ds_read + 1 B load + 1 MFMA).
    float4x oacc = {0.f, 0.f, 0.f, 0.f};
#pragma unroll
    for (int k2 = 0; k2 < 9; ++k2) {
        int kh = k2 / 3, kw = k2 - kh * 3;
        int pos = (plh + 2 + kh) * 15 + (plw + 2 + kw);
        int abase = pos * 72 + (lq << 3);
#pragma unroll
        for (int hf = 0; hf < 2; ++hf) {
            int kk = k2 * 2 + hf;
            short8x a = *(const short8x*)&tile[abase + hf * 32];
            short8x bo = *(const short8x*)&Bo[(kk * 2 + half) * 512 + (lane << 3)];
            oacc = __builtin_amdgcn_mfma_f32_16x16x32_bf16(a, bo, oacc, 0, 0, 0);
        }
    }
    {   // scatter D (col n = 16*half + l15, row = lq*4+r) + bias -> offl
        int n = (half << 4) + l15;
        if (n < 18) {
            float bo = boff[n];
#pragma unroll
            for (int r = 0; r < 4; ++r) {
                int p = (wq << 4) + (lq << 2) + r;
                offl[p * 18 + n] = oacc[r] + bo;
            }
        }
    }
    __syncthreads();

    // ---- offsets to registers (constant-indexed only) + oob mask
    float2 offr[9];
    uint oobmask = 0;
#pragma unroll
    for (int k2 = 0; k2 < 9; ++k2) {
        offr[k2] = *(const float2*)&offl[p1 * 18 + k2 * 2];
        const int kh = k2 / 3, kw = k2 - kh * 3;
        float sy = (float)(plh + 2 + kh) + offr[k2].x;
        float sx = (float)(plw + 2 + kw) + offr[k2].y;
        int by = (int)floorf(sy), bx = (int)floorf(sx);
        bool oob = ((unsigned)by > 13u) | ((unsigned)bx > 13u);
        oobmask |= oob ? (1u << k2) : 0u;
    }

    // ---- stage 2: 9 steps over this wave's cin-half (R9 loop body)
    float4x acc[4];
#pragma unroll
    for (int nt = 0; nt < 4; ++nt) acc[nt] = (float4x){0.f, 0.f, 0.f, 0.f};

#pragma unroll
    for (int k2 = 0; k2 < 9; ++k2) {
        const int kh = k2 / 3, kw = k2 - kh * 3;
        float sy = (float)(plh + 2 + kh) + offr[k2].x;
        float sx = (float)(plw + 2 + kw) + offr[k2].y;
        float yf = floorf(sy), xf = floorf(sx);
        int by = (int)yf, bx = (int)xf;
        float wy1 = sy - yf, wx1 = sx - xf;
        float wy0 = 1.f - wy1, wx0 = 1.f - wx1;
        float w00 = wy0 * wx0, w01 = wy0 * wx1;
        float w10 = wy1 * wx0, w11 = wy1 * wx1;
        int byc = min(max(by, 0), 13), bxc = min(max(bx, 0), 13);
        int cb = (byc * 15 + bxc) * 72 + (lq << 3) + (half << 5);

        int kk = k2 * 2 + half;
        short8x c00 = *(const short8x*)&tile[cb];
        short8x c01 = *(const short8x*)&tile[cb + 72];
        short8x c10 = *(const short8x*)&tile[cb + 72 * 15];
        short8x c11 = *(const short8x*)&tile[cb + 72 * 16];
        float s[8];
#pragma unroll
        for (int j = 0; j < 8; ++j) {
            s[j] = w00 * bf2f((ushort)c00[j]) + w01 * bf2f((ushort)c01[j])
                 + w10 * bf2f((ushort)c10[j]) + w11 * bf2f((ushort)c11[j]);
        }
        union { short8x v; ushort u[8]; } A;
#pragma unroll
        for (int j = 0; j < 8; ++j) A.u[j] = f2bf(s[j]);
#pragma unroll
        for (int nt = 0; nt < 4; ++nt) {
            short8x bw = *(const short8x*)&Bd[(kk * 4 + nt) * 512 + (lane << 3)];
            acc[nt] = __builtin_amdgcn_mfma_f32_16x16x32_bf16(A.v, bw, acc[nt], 0, 0, 0);
        }
    }

    // ---- cold exactness pass (own half): out-of-tile samples (~8 sigma,
    // never taken on this data). Recomputes from offl (LDS); no dynamic
    // indexing of register arrays (R8 lesson).
    if (__any(oobmask != 0)) {
#pragma unroll 1
        for (int k2 = 0; k2 < 9; ++k2) {
            if (!__any((oobmask >> k2) & 1)) continue;
            bool oob = (oobmask >> k2) & 1;
            const int kh = k2 / 3, kw = k2 - kh * 3;
            float2 od = *(const float2*)&offl[p1 * 18 + k2 * 2];
            float sy = (float)(plh + 2 + kh) + od.x;
            float sx = (float)(plw + 2 + kw) + od.y;
            float yf = floorf(sy), xf = floorf(sx);
            int by = (int)yf, bx = (int)xf;
            float wy1 = sy - yf, wx1 = sx - xf;
            float wy0 = 1.f - wy1, wx0 = 1.f - wx1;
            float w00 = wy0 * wx0, w01 = wy0 * wx1;
            float w10 = wy1 * wx0, w11 = wy1 * wx1;
            int byc = min(max(by, 0), 13), bxc = min(max(bx, 0), 13);
            int cb = (byc * 15 + bxc) * 72 + (lq << 3) + (half << 5);
            int y0g = by + h0 - 3, x0g = bx + w0 - 3;
            int y1g = y0g + 1, x1g = x0g + 1;
            float m00 = ((unsigned)y0g < 128u && (unsigned)x0g < 128u) ? w00 : 0.f;
            float m01 = ((unsigned)y0g < 128u && (unsigned)x1g < 128u) ? w01 : 0.f;
            float m10 = ((unsigned)y1g < 128u && (unsigned)x0g < 128u) ? w10 : 0.f;
            float m11 = ((unsigned)y1g < 128u && (unsigned)x1g < 128u) ? w11 : 0.f;
            int y0c = min(max(y0g, 0), 127), y1c = min(max(y1g, 0), 127);
            int x0c = min(max(x0g, 0), 127), x1c = min(max(x1g, 0), 127);
            int i00 = (y0c << 7) + x0c, i01 = (y0c << 7) + x1c;
            int i10 = (y1c << 7) + x0c, i11 = (y1c << 7) + x1c;
            int kk = k2 * 2 + half;
            int cin0 = (half << 5) + (lq << 3);
            short8x c00 = *(const short8x*)&tile[cb];
            short8x c01 = *(const short8x*)&tile[cb + 72];
            short8x c10 = *(const short8x*)&tile[cb + 72 * 15];
            short8x c11 = *(const short8x*)&tile[cb + 72 * 16];
            float d[8];
#pragma unroll
            for (int j = 0; j < 8; ++j) {
                float sl = w00 * bf2f((ushort)c00[j]) + w01 * bf2f((ushort)c01[j])
                         + w10 * bf2f((ushort)c10[j]) + w11 * bf2f((ushort)c11[j]);
                const float* xp = xb + ((long)(cin0 + j) << 14);
                float sg = m00 * xp[i00] + m01 * xp[i01]
                         + m10 * xp[i10] + m11 * xp[i11];
                d[j] = oob ? (sg - sl) : 0.f;
            }
            union { short8x v; ushort u[8]; } A;
#pragma unroll
            for (int j = 0; j < 8; ++j) A.u[j] = f2bf(d[j]);
#pragma unroll
            for (int nt = 0; nt < 4; ++nt) {
                short8x bw = *(const short8x*)&Bd[(kk * 4 + nt) * 512 + (lane << 3)];
                acc[nt] = __builtin_amdgcn_mfma_f32_16x16x32_bf16(A.v, bw, acc[nt], 0, 0, 0);
            }
        }
    }

    // ---- reduce half pairs through LDS red[64][65] (pad-65: conflict-free;
    // doubles as the transpose layout for the store epilogue)
    __syncthreads();
    float* red = (float*)smem;   // 64*65*4 = 16640 B over tile
    if (half == 1) {
#pragma unroll
        for (int nt = 0; nt < 4; ++nt)
#pragma unroll
            for (int r = 0; r < 4; ++r) {
                int p = (wq << 4) + (lq << 2) + r;
                red[p * 65 + (nt << 4) + l15] = acc[nt][r];
            }
    }
    __syncthreads();
    if (half == 0) {
#pragma unroll
        for (int nt = 0; nt < 4; ++nt)
#pragma unroll
            for (int r = 0; r < 4; ++r) {
                int p = (wq << 4) + (lq << 2) + r;
                red[p * 65 + (nt << 4) + l15] += acc[nt][r];
            }
    }
    __syncthreads();

    // ---- store: 512 threads, thread = (cout n, row q); 2x float4 per thread
    {
        int n = tid >> 3, q = tid & 7;
        float bd = bdef[n];
        float* dst = out + (((long)(b * 64 + n)) << 14) + ((h0 + q) << 7) + w0;
        float v[8];
#pragma unroll
        for (int c = 0; c < 8; ++c) v[c] = red[(q * 8 + c) * 65 + n] + bd;
        float4x s0 = {v[0], v[1], v[2], v[3]};
        float4x s1 = {v[4], v[5], v[6], v[7]};
        *(float4x*)(dst) = s0;
        *(float4x*)(dst + 4) = s1;
    }
}

// ---------------------------------------------------------------------------
extern "C" void kernel_launch(void* const* d_in, const int* in_sizes, int n_in,
                              void* d_out, int out_size, void* d_ws, size_t ws_size,
                              hipStream_t stream) {
    const float* x     = (const float*)d_in[0];  // (4,64,128,128)
    const float* w_off = (const float*)d_in[1];  // (18,64,3,3)
    const float* b_off = (const float*)d_in[2];  // (18,)
    const float* w_def = (const float*)d_in[3];  // (64,64,3,3)
    const float* b_def = (const float*)d_in[4];  // (64,)
    float* out = (float*)d_out;                  // (4,64,128,128)

    ushort* Bd = (ushort*)d_ws;                  // 36864 bf16 = 73728 B
    ushort* Bo = Bd + 36864;                     // 18432 bf16 = 36864 B

    hipLaunchKernelGGL(pack_weights, dim3(216), dim3(256), 0, stream,
                       w_def, w_off, Bd, Bo);
    hipLaunchKernelGGL(dcn_fused, dim3(1024), dim3(512), 0, stream,
                       x, Bd, Bo, b_off, b_def, out);
}